// Round 13
// baseline (630.202 us; speedup 1.0000x reference)
//
#include <hip/hip_runtime.h>

#define TT 2048
#define BB 2
#define DD 1024
#define HH 16
#define HD 64
#define FF 4096
#define EE 8
#define SS (TT*BB)     // 4096 tokens
#define CAP 1024       // 2*ceil(S/E)
#define EPSF 1.1920929e-07f

typedef __attribute__((ext_vector_type(8))) short short8;
typedef __attribute__((ext_vector_type(4))) float floatx4;

static __device__ inline unsigned short f2bf(float f){
    unsigned int u = __float_as_uint(f);
    unsigned int r = (u + 0x7fffu + ((u>>16)&1u)) >> 16;
    return (unsigned short)r;
}
static __device__ inline float bf2f(unsigned short h){
    return __uint_as_float(((unsigned int)h)<<16);
}
// round-to-nearest split
static __device__ inline void split2(float x, unsigned short& h, unsigned short& l){
    unsigned short hh = f2bf(x);
    h = hh;
    l = f2bf(x - bf2f(hh));
}
#define GETF4(v,j) ((j)==0?(v).x:(j)==1?(v).y:(j)==2?(v).z:(v).w)

// async global->LDS, 16B/lane: LDS dest = wave-uniform base + lane*16
typedef const __attribute__((address_space(1))) void gv_t;
typedef __attribute__((address_space(3))) void lv_t;
#define GLOAD16(gp, lp) __builtin_amdgcn_global_load_lds((gv_t*)(gp), (lv_t*)(lp), 16, 0, 0)

// ---------------- LayerNorm (f32 out; LN2/routing path) ----------------------
__global__ __launch_bounds__(256) void ln_kernel(const float* __restrict__ x,
    const float* __restrict__ gam, const float* __restrict__ bet, float* __restrict__ o)
{
    int row = blockIdx.x;
    int tid = threadIdx.x;
    float4 v = ((const float4*)(x + (size_t)row*DD))[tid];
    float s  = v.x+v.y+v.z+v.w;
    float ss = v.x*v.x+v.y*v.y+v.z*v.z+v.w*v.w;
    __shared__ float r1[256], r2[256];
    r1[tid]=s; r2[tid]=ss;
    __syncthreads();
    for (int off=128; off>0; off>>=1){
        if (tid<off){ r1[tid]+=r1[tid+off]; r2[tid]+=r2[tid+off]; }
        __syncthreads();
    }
    float mean = r1[0] * (1.f/DD);
    float var  = r2[0] * (1.f/DD) - mean*mean;
    float inv  = 1.f / sqrtf(var + 1e-5f);
    float4 g = ((const float4*)gam)[tid];
    float4 b = ((const float4*)bet)[tid];
    float4 r;
    r.x = (v.x-mean)*inv*g.x + b.x;
    r.y = (v.y-mean)*inv*g.y + b.y;
    r.z = (v.z-mean)*inv*g.z + b.z;
    r.w = (v.w-mean)*inv*g.w + b.w;
    ((float4*)(o + (size_t)row*DD))[tid] = r;
}

// ---------------- LayerNorm with pre-split bf16 hi/lo output (LN1) -----------
__global__ __launch_bounds__(256) void ln_split_kernel(const float* __restrict__ x,
    const float* __restrict__ gam, const float* __restrict__ bet,
    unsigned short* __restrict__ oh, unsigned short* __restrict__ ol)
{
    int row = blockIdx.x;
    int tid = threadIdx.x;
    float4 v = ((const float4*)(x + (size_t)row*DD))[tid];
    float s  = v.x+v.y+v.z+v.w;
    float ss = v.x*v.x+v.y*v.y+v.z*v.z+v.w*v.w;
    __shared__ float r1[256], r2[256];
    r1[tid]=s; r2[tid]=ss;
    __syncthreads();
    for (int off=128; off>0; off>>=1){
        if (tid<off){ r1[tid]+=r1[tid+off]; r2[tid]+=r2[tid+off]; }
        __syncthreads();
    }
    float mean = r1[0] * (1.f/DD);
    float var  = r2[0] * (1.f/DD) - mean*mean;
    float inv  = 1.f / sqrtf(var + 1e-5f);
    float4 g = ((const float4*)gam)[tid];
    float4 b = ((const float4*)bet)[tid];
    float4 r;
    r.x = (v.x-mean)*inv*g.x + b.x;
    r.y = (v.y-mean)*inv*g.y + b.y;
    r.z = (v.z-mean)*inv*g.z + b.z;
    r.w = (v.w-mean)*inv*g.w + b.w;
    ushort4 hv, lv;
    split2(r.x, hv.x, lv.x);
    split2(r.y, hv.y, lv.y);
    split2(r.z, hv.z, lv.z);
    split2(r.w, hv.w, lv.w);
    ((ushort4*)(oh + (size_t)row*DD))[tid] = hv;
    ((ushort4*)(ol + (size_t)row*DD))[tid] = lv;
}

// ---------------- bf16 MFMA GEMM (FFN): 2-phase global_load_lds dbuf ---------
// T3-minimum: issue next-tile gload_lds BEFORE computing current tile.
// Statically-named buffer pairs + 2x-unrolled loop so the compiler can
// disambiguate LDS accesses (no forced vmcnt drain before ds_reads).
// Staging: linear LDS dest + inverse-XOR-swizzled global source (rule #21,
// addressing bit-verified in R5); read applies the same XOR.
template<bool RELU, bool OUTBF16>
__global__ __launch_bounds__(256) void gemm_mfma(
    const unsigned short* __restrict__ A, const unsigned short* __restrict__ Bt,
    const float* __restrict__ bias, float* __restrict__ Cf,
    unsigned short* __restrict__ Cb,
    int M, int N, int K, long wStride, int bStride, int rowsPerExp)
{
    __shared__ unsigned short As0[128*64], Bs0[128*64];
    __shared__ unsigned short As1[128*64], Bs1[128*64];
    const int tid = threadIdx.x, lane = tid&63;
    const int w = tid>>6, wr = w>>1, wc = w&1;
    // bijective XCD swizzle (nwg % 8 == 0 for all FFN grids here)
    int gx = gridDim.x;
    int nwg = gx*gridDim.y;
    int flat = blockIdx.y*gx + blockIdx.x;
    int qq = nwg>>3;
    flat = (flat&7)*qq + (flat>>3);
    const int m0 = (flat/gx)*128, n0 = (flat%gx)*128;
    const int e = m0 / rowsPerExp;
    const unsigned short* Bp = Bt + (size_t)e*wStride;
    // staging: lane covers row r8=lane>>3 of each 8-row chunk,
    // source octet = (lane&7) ^ r8 (inverse swizzle; LDS dest linear)
    const int r8 = lane>>3, so2 = ((lane&7) ^ r8)*8;
    floatx4 zf = {0.f,0.f,0.f,0.f};
    floatx4 acc[4][4];
    #pragma unroll
    for (int m=0;m<4;m++)
        #pragma unroll
        for (int n=0;n<4;n++) acc[m][n]=zf;

    #define STAGE_FFN(ABUF,BBUF,KT) { \
        _Pragma("unroll") \
        for (int i=0;i<4;i++){ \
            int rbase = w*32 + i*8; \
            GLOAD16(A  + (size_t)(m0+rbase+r8)*K + (KT)*64 + so2, &ABUF[rbase*64]); \
            GLOAD16(Bp + (size_t)(n0+rbase+r8)*K + (KT)*64 + so2, &BBUF[rbase*64]); \
        } }
    #define MFMA_FFN(ABUF,BBUF) { \
        _Pragma("unroll") \
        for (int kk=0;kk<2;kk++){ \
            short8 af[4], bf[4]; \
            int kgrp = kk*4 + (lane>>4); \
            _Pragma("unroll") \
            for (int m=0;m<4;m++){ \
                int rowa = wr*64 + m*16 + (lane&15); \
                af[m] = *(const short8*)(&ABUF[rowa*64 + ((kgrp ^ (rowa&7))<<3)]); \
                int rowb = wc*64 + m*16 + (lane&15); \
                bf[m] = *(const short8*)(&BBUF[rowb*64 + ((kgrp ^ (rowb&7))<<3)]); \
            } \
            _Pragma("unroll") \
            for (int m=0;m<4;m++) \
                _Pragma("unroll") \
                for (int n=0;n<4;n++) \
                    acc[m][n] = __builtin_amdgcn_mfma_f32_16x16x32_bf16(af[m], bf[n], acc[m][n], 0,0,0); \
        } }

    // prologue: stage tile 0 into buf0
    STAGE_FFN(As0, Bs0, 0);
    __syncthreads();
    const int NT = K/64;   // 16 (FFN1) or 64 (FFN2): both even
    for (int kt=0; kt<NT; kt+=2){
        STAGE_FFN(As1, Bs1, kt+1);     // issue async loads for kt+1
        MFMA_FFN(As0, Bs0);            // compute kt (loads in flight)
        __syncthreads();               // drains vmcnt; buf1 ready
        if (kt+2 < NT){
            STAGE_FFN(As0, Bs0, kt+2); // issue async loads for kt+2
        }
        MFMA_FFN(As1, Bs1);            // compute kt+1
        __syncthreads();
    }
    #undef STAGE_FFN
    #undef MFMA_FFN

    int colg = n0 + wc*64 + (lane&15);
    int rowg = m0 + wr*64 + ((lane>>4)<<2);
    #pragma unroll
    for (int n=0;n<4;n++){
        float bv = bias[e*bStride + colg + n*16];
        #pragma unroll
        for (int m=0;m<4;m++){
            #pragma unroll
            for (int i2=0;i2<4;i2++){
                float v = acc[m][n][i2] + bv;
                if (RELU) v = fmaxf(v, 0.f);
                size_t o = (size_t)(rowg + m*16 + i2)*N + colg + n*16;
                if (OUTBF16) Cb[o] = f2bf(v); else Cf[o] = v;
            }
        }
    }
}

// ---------------- split-bf16x3 MFMA GEMM, PRE-SPLIT A (R12 dbuf) -------------
// QKV=true: chunk 0 -> f32 q (scale .125), chunk 1 -> split K hi/lo,
//           chunk 2 -> V single RN-bf16 (full 3-term compute; storage rounded).
template<bool QKV>
__global__ __launch_bounds__(256) void gemm_mfma_s(
    const unsigned short* __restrict__ Ahi, const unsigned short* __restrict__ Alo,
    const unsigned short* __restrict__ Bhi, const unsigned short* __restrict__ Blo,
    const float* __restrict__ b0, const float* __restrict__ b1p, const float* __restrict__ b2p,
    const float* __restrict__ res,
    float* __restrict__ o0,
    unsigned short* __restrict__ kh, unsigned short* __restrict__ kl,
    unsigned short* __restrict__ vh,
    int M, int K)
{
    __shared__ unsigned short As[2][128*64];   // row: [hi k0..31 | lo k0..31] octet-swizzled
    __shared__ unsigned short Bs[2][128*64];
    const int tid = threadIdx.x, lane = tid&63;
    const int w = tid>>6, wr = w>>1, wc = w&1;
    const int m0 = blockIdx.y*128, n0 = blockIdx.x*128;
    const int row = tid>>1, khalf = tid&1;
    floatx4 zf = {0.f,0.f,0.f,0.f};
    floatx4 acc[4][4];
    #pragma unroll
    for (int m=0;m<4;m++)
        #pragma unroll
        for (int n=0;n<4;n++) acc[m][n]=zf;

    short8 awh0,awh1,awl0,awl1, bwh0,bwh1,bwl0,bwl1;
    {
        size_t ao = (size_t)(m0+row)*K + khalf*16;
        awh0 = *(const short8*)(Ahi+ao); awh1 = *(const short8*)(Ahi+ao+8);
        awl0 = *(const short8*)(Alo+ao); awl1 = *(const short8*)(Alo+ao+8);
        size_t bo = (size_t)(n0+row)*K + khalf*16;
        bwh0 = *(const short8*)(Bhi+bo); bwh1 = *(const short8*)(Bhi+bo+8);
        bwl0 = *(const short8*)(Blo+bo); bwl1 = *(const short8*)(Blo+bo+8);
    }
    {
        int base = row*64, sw = row&7;
        int g0 = khalf*2, g1 = khalf*2+1;
        *(short8*)(&As[0][base + ((g0^sw)<<3)])     = awh0;
        *(short8*)(&As[0][base + ((g1^sw)<<3)])     = awh1;
        *(short8*)(&As[0][base + (((g0+4)^sw)<<3)]) = awl0;
        *(short8*)(&As[0][base + (((g1+4)^sw)<<3)]) = awl1;
        *(short8*)(&Bs[0][base + ((g0^sw)<<3)])     = bwh0;
        *(short8*)(&Bs[0][base + ((g1^sw)<<3)])     = bwh1;
        *(short8*)(&Bs[0][base + (((g0+4)^sw)<<3)]) = bwl0;
        *(short8*)(&Bs[0][base + (((g1+4)^sw)<<3)]) = bwl1;
    }
    __syncthreads();
    const int NT = K/32;
    int cur = 0;
    for (int kt=0; kt<NT; kt++){
        if (kt+1 < NT){
            int k0 = (kt+1)*32;
            size_t ao = (size_t)(m0+row)*K + k0 + khalf*16;
            awh0 = *(const short8*)(Ahi+ao); awh1 = *(const short8*)(Ahi+ao+8);
            awl0 = *(const short8*)(Alo+ao); awl1 = *(const short8*)(Alo+ao+8);
            size_t bo = (size_t)(n0+row)*K + k0 + khalf*16;
            bwh0 = *(const short8*)(Bhi+bo); bwh1 = *(const short8*)(Bhi+bo+8);
            bwl0 = *(const short8*)(Blo+bo); bwl1 = *(const short8*)(Blo+bo+8);
        }
        {
            int kg = lane>>4;
            short8 afh[4], afl[4], bfh[4], bfl[4];
            #pragma unroll
            for (int m=0;m<4;m++){
                int ra = wr*64 + m*16 + (lane&15);
                afh[m] = *(const short8*)(&As[cur][ra*64 + ((kg ^ (ra&7))<<3)]);
                afl[m] = *(const short8*)(&As[cur][ra*64 + (((kg+4) ^ (ra&7))<<3)]);
                int rb = wc*64 + m*16 + (lane&15);
                bfh[m] = *(const short8*)(&Bs[cur][rb*64 + ((kg ^ (rb&7))<<3)]);
                bfl[m] = *(const short8*)(&Bs[cur][rb*64 + (((kg+4) ^ (rb&7))<<3)]);
            }
            #pragma unroll
            for (int m=0;m<4;m++)
                #pragma unroll
                for (int n=0;n<4;n++){
                    acc[m][n] = __builtin_amdgcn_mfma_f32_16x16x32_bf16(afl[m], bfh[n], acc[m][n], 0,0,0);
                    acc[m][n] = __builtin_amdgcn_mfma_f32_16x16x32_bf16(afh[m], bfl[n], acc[m][n], 0,0,0);
                    acc[m][n] = __builtin_amdgcn_mfma_f32_16x16x32_bf16(afh[m], bfh[n], acc[m][n], 0,0,0);
                }
        }
        if (kt+1 < NT){
            int nb = cur^1;
            int base = row*64, sw = row&7;
            int g0 = khalf*2, g1 = khalf*2+1;
            *(short8*)(&As[nb][base + ((g0^sw)<<3)])     = awh0;
            *(short8*)(&As[nb][base + ((g1^sw)<<3)])     = awh1;
            *(short8*)(&As[nb][base + (((g0+4)^sw)<<3)]) = awl0;
            *(short8*)(&As[nb][base + (((g1+4)^sw)<<3)]) = awl1;
            *(short8*)(&Bs[nb][base + ((g0^sw)<<3)])     = bwh0;
            *(short8*)(&Bs[nb][base + ((g1^sw)<<3)])     = bwh1;
            *(short8*)(&Bs[nb][base + (((g0+4)^sw)<<3)]) = bwl0;
            *(short8*)(&Bs[nb][base + (((g1+4)^sw)<<3)]) = bwl1;
            __syncthreads();
            cur = nb;
        }
    }
    int colg = n0 + wc*64 + (lane&15);
    int rowg = m0 + wr*64 + ((lane>>4)<<2);
    if (QKV){
        int chunk = n0>>10;
        int colc = colg & 1023;
        const float* bp = chunk==0 ? b0 : (chunk==1 ? b1p : b2p);
        #pragma unroll
        for (int n=0;n<4;n++){
            float bv = bp[colc + n*16];
            #pragma unroll
            for (int m=0;m<4;m++){
                #pragma unroll
                for (int i2=0;i2<4;i2++){
                    int r = rowg + m*16 + i2;
                    float v = acc[m][n][i2] + bv;
                    size_t off = (size_t)r*DD + colc + n*16;
                    if (chunk==0){
                        o0[off] = v*0.125f;
                    } else if (chunk==1){
                        unsigned short hh, ll;
                        split2(v, hh, ll);
                        kh[off]=hh; kl[off]=ll;
                    } else {
                        vh[off] = f2bf(v);   // V stored RN-bf16 single
                    }
                }
            }
        }
    } else {
        #pragma unroll
        for (int n=0;n<4;n++){
            float bv = b0[colg + n*16];
            #pragma unroll
            for (int m=0;m<4;m++){
                #pragma unroll
                for (int i2=0;i2<4;i2++){
                    int r = rowg + m*16 + i2;
                    float v = acc[m][n][i2] + bv + res[(size_t)r*DD + colg + n*16];
                    o0[(size_t)r*DD + colg + n*16] = v;
                }
            }
        }
    }
}

// ---------------- split-bf16x3 MFMA flash attention (unchanged R9) -----------
__global__ __launch_bounds__(512) void attn_mfma(const float* __restrict__ q,
    const unsigned short* __restrict__ khi, const unsigned short* __restrict__ klo,
    const unsigned short* __restrict__ vbf,
    unsigned short* __restrict__ ohi, unsigned short* __restrict__ olo)
{
    __shared__ unsigned short Kh[128*64], Kl[128*64];   // 16KB each
    __shared__ unsigned short Vb[64*128];               // 16KB, transposed [d][s]
    __shared__ unsigned short Ph[8*16*64];              // 16KB, per-wave 16x64 half
    const int tid = threadIdx.x, lane = tid&63, w = tid>>6;   // w: 0..7
    const int t0 = blockIdx.x*128;
    const int b = blockIdx.y>>4, h = blockIdx.y&15;

    short8 qh[2], ql[2];
    #pragma unroll
    for (int kk=0;kk<2;kk++){
        const float* qp = q + ((size_t)(t0 + 16*w + (lane&15))*BB + b)*DD + h*64 + kk*32 + (lane>>4)*8;
        float4 f0 = ((const float4*)qp)[0];
        float4 f1 = ((const float4*)qp)[1];
        unsigned short hh[8], ll[8];
        #pragma unroll
        for (int j=0;j<4;j++){ split2(GETF4(f0,j), hh[j], ll[j]); }
        #pragma unroll
        for (int j=0;j<4;j++){ split2(GETF4(f1,j), hh[4+j], ll[4+j]); }
        qh[kk] = *(short8*)hh; ql[kk] = *(short8*)ll;
    }

    const int kr = tid>>2, kq = tid&3;            // K: row kr (0..127), octets 2kq,2kq+1
    const int vs0 = (tid&63)*2, vd0 = (tid>>6)*8; // V: 2 tokens x 8 dims
    short8 kwh0,kwh1,kwl0,kwl1, vw0,vw1;
    {
        size_t ko = ((size_t)kr*BB + b)*DD + h*64 + kq*16;
        kwh0 = *(const short8*)(khi+ko); kwh1 = *(const short8*)(khi+ko+8);
        kwl0 = *(const short8*)(klo+ko); kwl1 = *(const short8*)(klo+ko+8);
        size_t vo = ((size_t)vs0*BB + b)*DD + h*64 + vd0;
        vw0 = *(const short8*)(vbf+vo);
        vw1 = *(const short8*)(vbf+vo + (size_t)BB*DD);
    }

    float m_st[4] = {-3.0e38f,-3.0e38f,-3.0e38f,-3.0e38f};
    float l_st[4] = {0.f,0.f,0.f,0.f};
    floatx4 zf = {0.f,0.f,0.f,0.f};
    floatx4 oacc[4];
    #pragma unroll
    for (int n=0;n<4;n++) oacc[n]=zf;

    for (int s0=0; s0<TT; s0+=128){
        __syncthreads();
        {
            int base = kr*64, sw = kr&7;
            int g0 = kq*2, g1 = kq*2+1;
            *(short8*)(&Kh[base + ((g0^sw)<<3)]) = kwh0;
            *(short8*)(&Kh[base + ((g1^sw)<<3)]) = kwh1;
            *(short8*)(&Kl[base + ((g0^sw)<<3)]) = kwl0;
            *(short8*)(&Kl[base + ((g1^sw)<<3)]) = kwl1;
        }
        {
            int g = vs0>>3, so = vs0&7;
            #pragma unroll
            for (int j=0;j<8;j++){
                int d = vd0 + j;
                ushort2 pv;
                pv.x = (unsigned short)vw0[j];
                pv.y = (unsigned short)vw1[j];
                *(ushort2*)(&Vb[d*128 + ((g ^ (d&7))<<3) + so]) = pv;
            }
        }
        __syncthreads();
        if (s0+128 < TT){
            size_t ko = ((size_t)(s0+128+kr)*BB + b)*DD + h*64 + kq*16;
            kwh0 = *(const short8*)(khi+ko); kwh1 = *(const short8*)(khi+ko+8);
            kwl0 = *(const short8*)(klo+ko); kwl1 = *(const short8*)(klo+ko+8);
            size_t vo = ((size_t)(s0+128+vs0)*BB + b)*DD + h*64 + vd0;
            vw0 = *(const short8*)(vbf+vo);
            vw1 = *(const short8*)(vbf+vo + (size_t)BB*DD);
        }
        floatx4 sacc[8];
        __builtin_amdgcn_s_setprio(1);
        #pragma unroll
        for (int n=0;n<8;n++){
            floatx4 s = zf;
            #pragma unroll
            for (int kk=0;kk<2;kk++){
                int g = kk*4 + (lane>>4);
                int rb = n*16 + (lane&15);
                short8 kbh = *(const short8*)(&Kh[rb*64 + ((g ^ (rb&7))<<3)]);
                short8 kbl = *(const short8*)(&Kl[rb*64 + ((g ^ (rb&7))<<3)]);
                s = __builtin_amdgcn_mfma_f32_16x16x32_bf16(ql[kk], kbh, s, 0,0,0);
                s = __builtin_amdgcn_mfma_f32_16x16x32_bf16(qh[kk], kbl, s, 0,0,0);
                s = __builtin_amdgcn_mfma_f32_16x16x32_bf16(qh[kk], kbh, s, 0,0,0);
            }
            sacc[n] = s;
        }
        __builtin_amdgcn_s_setprio(0);
        float mx[4];
        #pragma unroll
        for (int r=0;r<4;r++){
            float a0 = fmaxf(fmaxf(sacc[0][r], sacc[1][r]), fmaxf(sacc[2][r], sacc[3][r]));
            float a1 = fmaxf(fmaxf(sacc[4][r], sacc[5][r]), fmaxf(sacc[6][r], sacc[7][r]));
            mx[r] = fmaxf(a0, a1);
        }
        #pragma unroll
        for (int sh=1; sh<16; sh<<=1){
            #pragma unroll
            for (int r=0;r<4;r++) mx[r] = fmaxf(mx[r], __shfl_xor(mx[r], sh));
        }
        float corr[4];
        #pragma unroll
        for (int r=0;r<4;r++){
            float nm = fmaxf(m_st[r], mx[r]);
            corr[r] = __expf(m_st[r] - nm);
            m_st[r] = nm;
        }
        float ts[4] = {0.f,0.f,0.f,0.f};
        #pragma unroll
        for (int n=0;n<8;n++){
            #pragma unroll
            for (int r=0;r<4;r++){
                float p = __expf(sacc[n][r] - m_st[r]);
                ts[r] += p;
                sacc[n][r] = p;
            }
        }
        #pragma unroll
        for (int sh=1; sh<16; sh<<=1){
            #pragma unroll
            for (int r=0;r<4;r++) ts[r] += __shfl_xor(ts[r], sh);
        }
        #pragma unroll
        for (int r=0;r<4;r++) l_st[r] = l_st[r]*corr[r] + ts[r];
        #pragma unroll
        for (int n=0;n<4;n++)
            #pragma unroll
            for (int r=0;r<4;r++) oacc[n][r] *= corr[r];
        #pragma unroll
        for (int half=0; half<2; half++){
            #pragma unroll
            for (int n2=0;n2<4;n2++){
                int n = half*4 + n2;
                #pragma unroll
                for (int r=0;r<4;r++){
                    int q2 = ((lane>>4)<<2) + r;
                    int s2 = n2*16 + (lane&15);
                    int off = w*1024 + q2*64 + (((s2>>3) ^ (q2&7))<<3) + (s2&7);
                    Ph[off] = f2bf(sacc[n][r]);
                }
            }
            __builtin_amdgcn_s_setprio(1);
            #pragma unroll
            for (int kk=0;kk<2;kk++){
                int g = kk*4 + (lane>>4);
                int rq = lane&15;
                short8 pa = *(const short8*)(&Ph[w*1024 + rq*64 + ((g ^ (rq&7))<<3)]);
                #pragma unroll
                for (int n=0;n<4;n++){
                    int rd = n*16 + (lane&15);
                    int gv = half*8 + g;
                    short8 vb = *(const short8*)(&Vb[rd*128 + ((gv ^ (rd&7))<<3)]);
                    oacc[n] = __builtin_amdgcn_mfma_f32_16x16x32_bf16(pa, vb, oacc[n], 0,0,0);
                }
            }
            __builtin_amdgcn_s_setprio(0);
        }
    }
    float il[4];
    #pragma unroll
    for (int r=0;r<4;r++) il[r] = 1.f/l_st[r];
    int qrow = t0 + 16*w + ((lane>>4)<<2);
    #pragma unroll
    for (int n=0;n<4;n++){
        #pragma unroll
        for (int r=0;r<4;r++){
            float v = oacc[n][r]*il[r];
            unsigned short hh, ll;
            split2(v, hh, ll);
            size_t off = ((size_t)(qrow+r)*BB + b)*DD + h*64 + n*16 + (lane&15);
            ohi[off] = hh; olo[off] = ll;
        }
    }
}

// ---------------- transpose+convert bf16 (FFN weights) -----------------------
__global__ __launch_bounds__(256) void transpose_bf16_k(const float* __restrict__ in,
    unsigned short* __restrict__ outp, int R, int C)
{
    __shared__ float t[64][65];
    int e = blockIdx.z;
    const float* ip = in + (size_t)e*R*C;
    unsigned short* op = outp + (size_t)e*R*C;
    int r0 = blockIdx.y*64, c0 = blockIdx.x*64;
    int tid = threadIdx.x;
    #pragma unroll
    for (int i=0;i<4;i++){
        int ch = i*256 + tid;
        int r = ch>>4, c4 = (ch&15)*4;
        float4 v = *(const float4*)(ip + (size_t)(r0+r)*C + c0 + c4);
        t[r][c4+0]=v.x; t[r][c4+1]=v.y; t[r][c4+2]=v.z; t[r][c4+3]=v.w;
    }
    __syncthreads();
    #pragma unroll
    for (int i=0;i<4;i++){
        int ch = i*256 + tid;
        int rr = ch>>4, c4 = (ch&15)*4;
        ushort4 o;
        o.x = f2bf(t[c4+0][rr]); o.y = f2bf(t[c4+1][rr]);
        o.z = f2bf(t[c4+2][rr]); o.w = f2bf(t[c4+3][rr]);
        *(ushort4*)(op + (size_t)(c0+rr)*R + r0 + c4) = o;
    }
}

// ---------------- transpose + split hi/lo (projection weights) ---------------
__global__ __launch_bounds__(256) void transpose_split_k(const float* __restrict__ in,
    unsigned short* __restrict__ oh, unsigned short* __restrict__ ol, int R, int C)
{
    __shared__ float t[64][65];
    int r0 = blockIdx.y*64, c0 = blockIdx.x*64;
    int tid = threadIdx.x;
    #pragma unroll
    for (int i=0;i<4;i++){
        int ch = i*256 + tid;
        int r = ch>>4, c4 = (ch&15)*4;
        float4 v = *(const float4*)(in + (size_t)(r0+r)*C + c0 + c4);
        t[r][c4+0]=v.x; t[r][c4+1]=v.y; t[r][c4+2]=v.z; t[r][c4+3]=v.w;
    }
    __syncthreads();
    #pragma unroll
    for (int i=0;i<4;i++){
        int ch = i*256 + tid;
        int rr = ch>>4, c4 = (ch&15)*4;
        ushort4 hv, lv;
        split2(t[c4+0][rr], hv.x, lv.x);
        split2(t[c4+1][rr], hv.y, lv.y);
        split2(t[c4+2][rr], hv.z, lv.z);
        split2(t[c4+3][rr], hv.w, lv.w);
        size_t off = (size_t)(c0+rr)*R + r0 + c4;
        *(ushort4*)(oh + off) = hv;
        *(ushort4*)(ol + off) = lv;
    }
}

// ---------------- gather dispatch buffer -------------------------------------
__global__ __launch_bounds__(256) void gather_bf16_k(const float* __restrict__ h2,
    const int* __restrict__ s2r, unsigned short* __restrict__ buf)
{
    int s = blockIdx.x; int row = s2r[s]; int c = threadIdx.x;
    float4 v = make_float4(0.f,0.f,0.f,0.f);
    if (row>=0) v = *(const float4*)(h2 + (size_t)row*DD + c*4);
    ushort4 o;
    o.x=f2bf(v.x); o.y=f2bf(v.y); o.z=f2bf(v.z); o.w=f2bf(v.w);
    *(ushort4*)(buf + (size_t)s*DD + c*4) = o;
}

// ---------------- Routing (unchanged) ----------------------------------------
__global__ __launch_bounds__(256) void route_kernel(const float* __restrict__ h2,
    const float* __restrict__ wgm, float* __restrict__ gates,
    int* __restrict__ idx1, int* __restrict__ idx2,
    float* __restrict__ g1, float* __restrict__ g2)
{
    int wid = threadIdx.x >> 6, lane = threadIdx.x & 63;
    int s = blockIdx.x*4 + wid;
    int row = (s % TT)*BB + (s / TT);
    const float* hr = h2 + (size_t)row*DD;
    float acc[EE] = {};
    #pragma unroll
    for (int c=0;c<16;c++){
        int d = c*64 + lane;
        float xv = hr[d];
        const float* wr = wgm + (size_t)d*EE;
        #pragma unroll
        for (int e2=0;e2<EE;e2++) acc[e2] += xv * wr[e2];
    }
    #pragma unroll
    for (int off=32; off>0; off>>=1){
        #pragma unroll
        for (int e2=0;e2<EE;e2++) acc[e2] += __shfl_down(acc[e2], off);
    }
    if (lane==0){
        float mx = acc[0];
        #pragma unroll
        for (int e2=1;e2<EE;e2++) mx = fmaxf(mx, acc[e2]);
        float ex[EE]; float sum=0.f;
        #pragma unroll
        for (int e2=0;e2<EE;e2++){ ex[e2] = __expf(acc[e2]-mx); sum += ex[e2]; }
        float inv = 1.f/sum;
        int i1=0; float bv1=acc[0];
        #pragma unroll
        for (int e2=1;e2<EE;e2++){ if (acc[e2] > bv1){ bv1=acc[e2]; i1=e2; } }
        int i2=-1; float bv2=-3.0e38f;
        #pragma unroll
        for (int e2=0;e2<EE;e2++){ if (e2!=i1 && acc[e2] > bv2){ bv2=acc[e2]; i2=e2; } }
        #pragma unroll
        for (int e2=0;e2<EE;e2++) gates[(size_t)s*EE + e2] = ex[e2]*inv;
        idx1[s]=i1; idx2[s]=i2;
        g1[s]=ex[i1]*inv; g2[s]=ex[i2]*inv;
    }
}

// ---------------- Single-block deterministic scan (unchanged) ----------------
__global__ __launch_bounds__(256) void scan_kernel(
    const float* __restrict__ gates, const int* __restrict__ idx1, const int* __restrict__ idx2,
    const float* __restrict__ g1, const float* __restrict__ g2,
    float* __restrict__ g1n, float* __restrict__ g2n,
    int* __restrict__ f1, int* __restrict__ f2, int* __restrict__ slot2row,
    float* __restrict__ laux)
{
    __shared__ int i1s[SS];
    __shared__ int i2s[SS];
    __shared__ int cnt1[256][EE];
    __shared__ int cnt2[256][EE];
    __shared__ float gsum[256][EE];
    __shared__ int tot1[EE];
    int tid = threadIdx.x;
    for (int i=tid;i<EE*CAP;i+=256) slot2row[i] = -1;
    for (int i=tid;i<SS;i+=256){ i1s[i]=idx1[i]; i2s[i]=idx2[i]; }
    __syncthreads();
    int c1l[EE]={}, c2l[EE]={};
    float gl[EE]={};
    int base = tid*16;
    for (int qq=0;qq<16;qq++){
        int s = base+qq;
        c1l[i1s[s]]++; c2l[i2s[s]]++;
        #pragma unroll
        for (int e2=0;e2<EE;e2++) gl[e2] += gates[(size_t)s*EE+e2];
    }
    #pragma unroll
    for (int e2=0;e2<EE;e2++){ cnt1[tid][e2]=c1l[e2]; cnt2[tid][e2]=c2l[e2]; gsum[tid][e2]=gl[e2]; }
    __syncthreads();
    if (tid < EE){
        int e2 = tid;
        int run=0;
        for (int t=0;t<256;t++){ int tmp=cnt1[t][e2]; cnt1[t][e2]=run; run+=tmp; }
        tot1[e2]=run;
        run=0;
        for (int t=0;t<256;t++){ int tmp=cnt2[t][e2]; cnt2[t][e2]=run; run+=tmp; }
        float gr=0.f;
        for (int t=0;t<256;t++) gr += gsum[t][e2];
        gsum[0][e2]=gr;
    }
    __syncthreads();
    int p1[EE], p2[EE];
    #pragma unroll
    for (int e2=0;e2<EE;e2++){ p1[e2]=cnt1[tid][e2]; p2[e2]=cnt2[tid][e2]+tot1[e2]; }
    for (int qq=0;qq<16;qq++){
        int s = base+qq;
        int e1 = i1s[s], e2v = i2s[s];
        int pos1 = p1[e1]++;
        int pos2 = p2[e2v]++;
        float gv1 = g1[s], gv2 = g2[s];
        float gm1 = (pos1<CAP)? gv1 : 0.f;
        float gm2 = (pos2<CAP)? gv2 : 0.f;
        float den = fmaxf(gm1+gm2, EPSF);
        g1n[s] = gm1/den; g2n[s] = gm2/den;
        int ff1 = e1*CAP + (pos1<CAP?pos1:CAP-1);
        int ff2 = e2v*CAP + (pos2<CAP?pos2:CAP-1);
        f1[s]=ff1; f2[s]=ff2;
        int hrow = (s % TT)*BB + (s / TT);
        if (pos1<CAP) slot2row[ff1]=hrow;
        if (pos2<CAP) slot2row[ff2]=hrow;
    }
    if (tid==0){
        float a=0.f;
        #pragma unroll
        for (int e2=0;e2<EE;e2++) a += (gsum[0][e2]*(1.f/SS)) * ((float)tot1[e2]*(1.f/SS));
        laux[0] = a * (float)EE;
    }
}

// ---------------- Combine (unchanged) ----------------------------------------
__global__ __launch_bounds__(256) void combine_kernel(const float* __restrict__ x2,
    const float* __restrict__ eout, const float* __restrict__ g1n, const float* __restrict__ g2n,
    const int* __restrict__ f1, const int* __restrict__ f2, float* __restrict__ out)
{
    int s = blockIdx.x;
    float a = g1n[s], b = g2n[s];
    int s1 = f1[s], s2 = f2[s];
    int row = (s % TT)*BB + (s / TT);
    int c = threadIdx.x;
    float4 o1 = ((const float4*)(eout + (size_t)s1*DD))[c];
    float4 o2 = ((const float4*)(eout + (size_t)s2*DD))[c];
    float4 xr = ((const float4*)(x2 + (size_t)row*DD))[c];
    float4 r;
    r.x = xr.x + a*o1.x + b*o2.x;
    r.y = xr.y + a*o1.y + b*o2.y;
    r.z = xr.z + a*o1.z + b*o2.z;
    r.w = xr.w + a*o1.w + b*o2.w;
    ((float4*)(out + (size_t)row*DD))[c] = r;
}

extern "C" void kernel_launch(void* const* d_in, const int* in_sizes, int n_in,
                              void* d_out, int out_size, void* d_ws, size_t ws_size,
                              hipStream_t stream)
{
    const float* x    = (const float*)d_in[0];
    const float* Wq   = (const float*)d_in[1];
    const float* bq   = (const float*)d_in[2];
    const float* Wk   = (const float*)d_in[3];
    const float* bk   = (const float*)d_in[4];
    const float* Wv   = (const float*)d_in[5];
    const float* bv   = (const float*)d_in[6];
    const float* Wo   = (const float*)d_in[7];
    const float* bo   = (const float*)d_in[8];
    const float* ln1g = (const float*)d_in[9];
    const float* ln1b = (const float*)d_in[10];
    const float* ln2g = (const float*)d_in[11];
    const float* ln2b = (const float*)d_in[12];
    const float* wgm  = (const float*)d_in[13];
    const float* W1   = (const float*)d_in[14];
    const float* b1   = (const float*)d_in[15];
    const float* W2   = (const float*)d_in[16];
    const float* b2   = (const float*)d_in[17];
    float* out = (float*)d_out;

    char* w = (char*)d_ws;
    unsigned short* h1hi = (unsigned short*)(w);                      // 8MB (later ohi)
    unsigned short* h1lo = (unsigned short*)(w + ((size_t)8<<20));    // 8MB (later olo)
    float*          qb   = (float*)(w + ((size_t)16<<20));     // 16MB (q f32, then h2)
    unsigned short* Khg  = (unsigned short*)(w + ((size_t)32<<20));   // 8MB bf16 [4096][1024]
    unsigned short* Klg  = (unsigned short*)(w + ((size_t)40<<20));   // 8MB
    unsigned short* Vhg  = (unsigned short*)(w + ((size_t)48<<20));   // 8MB (V RN-bf16)
    float*          x2   = (float*)(w + ((size_t)64<<20));     // 16MB
    unsigned short* bufb = (unsigned short*)(w + ((size_t)80<<20));   // 16MB bf16 dispatch
    unsigned short* hb   = (unsigned short*)(w + ((size_t)96<<20));   // 64MB bf16 FFN1 out
    unsigned short* Bqkv_hi = (unsigned short*)(w + ((size_t)96<<20));   // 6MB (dead before FFN1)
    unsigned short* Bqkv_lo = (unsigned short*)(w + ((size_t)102<<20));  // 6MB
    unsigned short* Bo_hi   = (unsigned short*)(w + ((size_t)108<<20));  // 2MB
    unsigned short* Bo_lo   = (unsigned short*)(w + ((size_t)110<<20));  // 2MB
    unsigned short* W1t  = (unsigned short*)(w + ((size_t)160<<20));  // 64MB
    unsigned short* W2t  = (unsigned short*)(w + ((size_t)224<<20));  // 64MB
    float*          ffno = (float*)(w + ((size_t)32<<20));     // 32MB f32 (reuses K/V bufs)
    char*  sm   = w + ((size_t)288<<20);
    float* gates   = (float*)(sm);                sm += (size_t)SS*EE*4;
    int*   idx1    = (int*)(sm);                  sm += SS*4;
    int*   idx2    = (int*)(sm);                  sm += SS*4;
    float* g1      = (float*)(sm);                sm += SS*4;
    float* g2      = (float*)(sm);                sm += SS*4;
    float* g1n     = (float*)(sm);                sm += SS*4;
    float* g2n     = (float*)(sm);                sm += SS*4;
    int*   f1      = (int*)(sm);                  sm += SS*4;
    int*   f2      = (int*)(sm);                  sm += SS*4;
    int*   slot2row= (int*)(sm);                  sm += EE*CAP*4;

    // 0. weight prep
    transpose_bf16_k<<<dim3(FF/64, DD/64, EE), 256, 0, stream>>>(W1, W1t, DD, FF);
    transpose_bf16_k<<<dim3(DD/64, FF/64, EE), 256, 0, stream>>>(W2, W2t, FF, DD);
    transpose_split_k<<<dim3(16,16), 256, 0, stream>>>(Wq, Bqkv_hi,                   Bqkv_lo,                   DD, DD);
    transpose_split_k<<<dim3(16,16), 256, 0, stream>>>(Wk, Bqkv_hi + (size_t)DD*DD,   Bqkv_lo + (size_t)DD*DD,   DD, DD);
    transpose_split_k<<<dim3(16,16), 256, 0, stream>>>(Wv, Bqkv_hi + (size_t)2*DD*DD, Bqkv_lo + (size_t)2*DD*DD, DD, DD);
    transpose_split_k<<<dim3(16,16), 256, 0, stream>>>(Wo, Bo_hi, Bo_lo, DD, DD);
    // 1. LN1 -> pre-split bf16 hi/lo
    ln_split_kernel<<<SS, 256, 0, stream>>>(x, ln1g, ln1b, h1hi, h1lo);
    // 2. fused QKV projection (dbuf); K split hi/lo, V RN-bf16 (3-term compute)
    gemm_mfma_s<true><<<dim3(24, SS/128), 256, 0, stream>>>(
        h1hi, h1lo, Bqkv_hi, Bqkv_lo, bq, bk, bv, nullptr, qb, Khg, Klg, Vhg, SS, DD);
    // 3. attention (128x128 tiles, 8 waves) -> pre-split O hi/lo
    attn_mfma<<<dim3(TT/128, BB*HH), 512, 0, stream>>>(qb, Khg, Klg, Vhg, h1hi, h1lo);
    // 4. O-projection + residual -> x2 (dbuf)
    gemm_mfma_s<false><<<dim3(8, SS/128), 256, 0, stream>>>(
        h1hi, h1lo, Bo_hi, Bo_lo, bo, bo, bo, x, x2, nullptr, nullptr, nullptr, SS, DD);
    // 5. LN2 -> h2 (qb)
    ln_kernel<<<SS, 256, 0, stream>>>(x2, ln2g, ln2b, qb);
    // 6. routing
    route_kernel<<<SS/4, 256, 0, stream>>>(qb, wgm, gates, idx1, idx2, g1, g2);
    // 7. scan
    scan_kernel<<<1, 256, 0, stream>>>(gates, idx1, idx2, g1, g2,
        g1n, g2n, f1, f2, slot2row, out + (size_t)SS*DD);
    // 8. gather dispatch buffer
    gather_bf16_k<<<EE*CAP, 256, 0, stream>>>(qb, slot2row, bufb);
    // 9. expert FFN (bf16 MFMA, 2-phase global_load_lds dbuf + XCD swizzle)
    gemm_mfma<true,true><<<dim3(FF/128, (EE*CAP)/128), 256, 0, stream>>>(
        bufb, W1t, b1, nullptr, hb, EE*CAP, FF, DD, (long)FF*DD, FF, CAP);
    gemm_mfma<false,false><<<dim3(DD/128, (EE*CAP)/128), 256, 0, stream>>>(
        hb, W2t, b2, ffno, nullptr, EE*CAP, DD, FF, (long)DD*FF, DD, CAP);
    // 10. combine + residual
    combine_kernel<<<SS, 256, 0, stream>>>(x2, ffno, g1n, g2n, f1, f2, out);
    (void)in_sizes; (void)n_in; (void)out_size; (void)ws_size;
}

// Round 14
// 606.281 us; speedup vs baseline: 1.0395x; 1.0395x over previous
//
#include <hip/hip_runtime.h>

#define TT 2048
#define BB 2
#define DD 1024
#define HH 16
#define HD 64
#define FF 4096
#define EE 8
#define SS (TT*BB)     // 4096 tokens
#define CAP 1024       // 2*ceil(S/E)
#define EPSF 1.1920929e-07f

typedef __attribute__((ext_vector_type(8))) short short8;
typedef __attribute__((ext_vector_type(4))) float floatx4;

static __device__ inline unsigned short f2bf(float f){
    unsigned int u = __float_as_uint(f);
    unsigned int r = (u + 0x7fffu + ((u>>16)&1u)) >> 16;
    return (unsigned short)r;
}
static __device__ inline float bf2f(unsigned short h){
    return __uint_as_float(((unsigned int)h)<<16);
}
// round-to-nearest split
static __device__ inline void split2(float x, unsigned short& h, unsigned short& l){
    unsigned short hh = f2bf(x);
    h = hh;
    l = f2bf(x - bf2f(hh));
}
#define GETF4(v,j) ((j)==0?(v).x:(j)==1?(v).y:(j)==2?(v).z:(v).w)

// ---------------- LayerNorm with pre-split bf16 hi/lo output (LN1) -----------
__global__ __launch_bounds__(256) void ln_split_kernel(const float* __restrict__ x,
    const float* __restrict__ gam, const float* __restrict__ bet,
    unsigned short* __restrict__ oh, unsigned short* __restrict__ ol)
{
    int row = blockIdx.x;
    int tid = threadIdx.x;
    float4 v = ((const float4*)(x + (size_t)row*DD))[tid];
    float s  = v.x+v.y+v.z+v.w;
    float ss = v.x*v.x+v.y*v.y+v.z*v.z+v.w*v.w;
    __shared__ float r1[256], r2[256];
    r1[tid]=s; r2[tid]=ss;
    __syncthreads();
    for (int off=128; off>0; off>>=1){
        if (tid<off){ r1[tid]+=r1[tid+off]; r2[tid]+=r2[tid+off]; }
        __syncthreads();
    }
    float mean = r1[0] * (1.f/DD);
    float var  = r2[0] * (1.f/DD) - mean*mean;
    float inv  = 1.f / sqrtf(var + 1e-5f);
    float4 g = ((const float4*)gam)[tid];
    float4 b = ((const float4*)bet)[tid];
    float4 r;
    r.x = (v.x-mean)*inv*g.x + b.x;
    r.y = (v.y-mean)*inv*g.y + b.y;
    r.z = (v.z-mean)*inv*g.z + b.z;
    r.w = (v.w-mean)*inv*g.w + b.w;
    ushort4 hv, lv;
    split2(r.x, hv.x, lv.x);
    split2(r.y, hv.y, lv.y);
    split2(r.z, hv.z, lv.z);
    split2(r.w, hv.w, lv.w);
    ((ushort4*)(oh + (size_t)row*DD))[tid] = hv;
    ((ushort4*)(ol + (size_t)row*DD))[tid] = lv;
}

// ---------------- fused LN2 + routing ----------------------------------------
// LN2 math identical to the old ln_kernel; wave 0 then replays route_kernel's
// EXACT accumulation order from LDS (bit-identical logits -> no routing risk).
__global__ __launch_bounds__(256) void ln2_route_kernel(const float* __restrict__ x,
    const float* __restrict__ gam, const float* __restrict__ bet, float* __restrict__ o,
    const float* __restrict__ wgm, float* __restrict__ gates,
    int* __restrict__ idx1, int* __restrict__ idx2,
    float* __restrict__ g1, float* __restrict__ g2)
{
    int row = blockIdx.x;
    int tid = threadIdx.x;
    float4 v = ((const float4*)(x + (size_t)row*DD))[tid];
    float s  = v.x+v.y+v.z+v.w;
    float ss = v.x*v.x+v.y*v.y+v.z*v.z+v.w*v.w;
    __shared__ float r1[256], r2[256];
    __shared__ float rowbuf[DD];
    r1[tid]=s; r2[tid]=ss;
    __syncthreads();
    for (int off=128; off>0; off>>=1){
        if (tid<off){ r1[tid]+=r1[tid+off]; r2[tid]+=r2[tid+off]; }
        __syncthreads();
    }
    float mean = r1[0] * (1.f/DD);
    float var  = r2[0] * (1.f/DD) - mean*mean;
    float inv  = 1.f / sqrtf(var + 1e-5f);
    float4 g = ((const float4*)gam)[tid];
    float4 b = ((const float4*)bet)[tid];
    float4 r;
    r.x = (v.x-mean)*inv*g.x + b.x;
    r.y = (v.y-mean)*inv*g.y + b.y;
    r.z = (v.z-mean)*inv*g.z + b.z;
    r.w = (v.w-mean)*inv*g.w + b.w;
    ((float4*)(o + (size_t)row*DD))[tid] = r;
    ((float4*)rowbuf)[tid] = r;
    __syncthreads();
    if (tid < 64){
        int lane = tid;
        // token index: row = t*BB + b  ->  s = b*TT + t
        int sTok = (row & (BB-1))*TT + (row >> 1);
        float acc[EE] = {};
        #pragma unroll
        for (int c=0;c<16;c++){
            int d = c*64 + lane;
            float xv = rowbuf[d];
            const float* wr = wgm + (size_t)d*EE;
            #pragma unroll
            for (int e2=0;e2<EE;e2++) acc[e2] += xv * wr[e2];
        }
        #pragma unroll
        for (int off=32; off>0; off>>=1){
            #pragma unroll
            for (int e2=0;e2<EE;e2++) acc[e2] += __shfl_down(acc[e2], off);
        }
        if (lane==0){
            float mx = acc[0];
            #pragma unroll
            for (int e2=1;e2<EE;e2++) mx = fmaxf(mx, acc[e2]);
            float ex[EE]; float sum=0.f;
            #pragma unroll
            for (int e2=0;e2<EE;e2++){ ex[e2] = __expf(acc[e2]-mx); sum += ex[e2]; }
            float invs = 1.f/sum;
            int i1=0; float bv1=acc[0];
            #pragma unroll
            for (int e2=1;e2<EE;e2++){ if (acc[e2] > bv1){ bv1=acc[e2]; i1=e2; } }
            int i2=-1; float bv2=-3.0e38f;
            #pragma unroll
            for (int e2=0;e2<EE;e2++){ if (e2!=i1 && acc[e2] > bv2){ bv2=acc[e2]; i2=e2; } }
            #pragma unroll
            for (int e2=0;e2<EE;e2++) gates[(size_t)sTok*EE + e2] = ex[e2]*invs;
            idx1[sTok]=i1; idx2[sTok]=i2;
            g1[sTok]=ex[i1]*invs; g2[sTok]=ex[i2]*invs;
        }
    }
}

// ---------------- plain bf16 MFMA GEMM (FFN; R11 proven: 2-barrier + swizzle) -
template<bool RELU, bool OUTBF16>
__global__ __launch_bounds__(256) void gemm_mfma(
    const unsigned short* __restrict__ A, const unsigned short* __restrict__ Bt,
    const float* __restrict__ bias, float* __restrict__ Cf,
    unsigned short* __restrict__ Cb,
    int M, int N, int K, long wStride, int bStride, int rowsPerExp)
{
    __shared__ unsigned short As[128*64];
    __shared__ unsigned short Bs[128*64];
    const int tid = threadIdx.x, lane = tid&63;
    const int w = tid>>6, wr = w>>1, wc = w&1;
    int gx = gridDim.x;
    int nwg = gx*gridDim.y;
    int flat = blockIdx.y*gx + blockIdx.x;
    int qq = nwg>>3;
    flat = (flat&7)*qq + (flat>>3);
    const int m0 = (flat/gx)*128, n0 = (flat%gx)*128;
    const int e = m0 / rowsPerExp;
    const unsigned short* Bp = Bt + (size_t)e*wStride;
    const int srow = tid>>3, sslot = tid&7;
    floatx4 zf = {0.f,0.f,0.f,0.f};
    floatx4 acc[4][4];
    #pragma unroll
    for (int m=0;m<4;m++)
        #pragma unroll
        for (int n=0;n<4;n++) acc[m][n]=zf;

    short8 ar[4], br[4];
    #pragma unroll
    for (int i=0;i<4;i++){
        int r = srow + i*32;
        ar[i] = *(const short8*)(A  + (size_t)(m0+r)*K + sslot*8);
        br[i] = *(const short8*)(Bp + (size_t)(n0+r)*K + sslot*8);
    }
    const int NT = K/64;
    for (int kt=0; kt<NT; kt++){
        __syncthreads();
        #pragma unroll
        for (int i=0;i<4;i++){
            int r = srow + i*32;
            int off = r*64 + ((sslot ^ (r&7))<<3);
            *(short8*)(&As[off]) = ar[i];
            *(short8*)(&Bs[off]) = br[i];
        }
        __syncthreads();
        if (kt+1 < NT){
            int k0 = (kt+1)*64;
            #pragma unroll
            for (int i=0;i<4;i++){
                int r = srow + i*32;
                ar[i] = *(const short8*)(A  + (size_t)(m0+r)*K + k0 + sslot*8);
                br[i] = *(const short8*)(Bp + (size_t)(n0+r)*K + k0 + sslot*8);
            }
        }
        #pragma unroll
        for (int kk=0;kk<2;kk++){
            short8 af[4], bf[4];
            int kgrp = kk*4 + (lane>>4);
            #pragma unroll
            for (int m=0;m<4;m++){
                int rowa = wr*64 + m*16 + (lane&15);
                af[m] = *(const short8*)(&As[rowa*64 + ((kgrp ^ (rowa&7))<<3)]);
                int rowb = wc*64 + m*16 + (lane&15);
                bf[m] = *(const short8*)(&Bs[rowb*64 + ((kgrp ^ (rowb&7))<<3)]);
            }
            #pragma unroll
            for (int m=0;m<4;m++)
                #pragma unroll
                for (int n=0;n<4;n++)
                    acc[m][n] = __builtin_amdgcn_mfma_f32_16x16x32_bf16(af[m], bf[n], acc[m][n], 0,0,0);
        }
    }
    int colg = n0 + wc*64 + (lane&15);
    int rowg = m0 + wr*64 + ((lane>>4)<<2);
    #pragma unroll
    for (int n=0;n<4;n++){
        float bv = bias[e*bStride + colg + n*16];
        #pragma unroll
        for (int m=0;m<4;m++){
            #pragma unroll
            for (int i2=0;i2<4;i2++){
                float v = acc[m][n][i2] + bv;
                if (RELU) v = fmaxf(v, 0.f);
                size_t o = (size_t)(rowg + m*16 + i2)*N + colg + n*16;
                if (OUTBF16) Cb[o] = f2bf(v); else Cf[o] = v;
            }
        }
    }
}

// ---------------- split-bf16x3 MFMA GEMM, PRE-SPLIT A (R11 proven) -----------
// QKV=true: chunk 0 -> f32 q (scale .125), chunk 1 -> split K hi/lo,
//           chunk 2 -> V single RN-bf16 (full 3-term compute; storage rounded).
template<bool QKV>
__global__ __launch_bounds__(256) void gemm_mfma_s(
    const unsigned short* __restrict__ Ahi, const unsigned short* __restrict__ Alo,
    const unsigned short* __restrict__ Bhi, const unsigned short* __restrict__ Blo,
    const float* __restrict__ b0, const float* __restrict__ b1p, const float* __restrict__ b2p,
    const float* __restrict__ res,
    float* __restrict__ o0,
    unsigned short* __restrict__ kh, unsigned short* __restrict__ kl,
    unsigned short* __restrict__ vh,
    int M, int K)
{
    __shared__ unsigned short As[128*64];   // row: [hi k0..31 | lo k0..31] octet-swizzled
    __shared__ unsigned short Bs[128*64];
    const int tid = threadIdx.x, lane = tid&63;
    const int w = tid>>6, wr = w>>1, wc = w&1;
    const int m0 = blockIdx.y*128, n0 = blockIdx.x*128;
    const int row = tid>>1, khalf = tid&1;
    floatx4 zf = {0.f,0.f,0.f,0.f};
    floatx4 acc[4][4];
    #pragma unroll
    for (int m=0;m<4;m++)
        #pragma unroll
        for (int n=0;n<4;n++) acc[m][n]=zf;

    short8 awh0,awh1,awl0,awl1, bwh0,bwh1,bwl0,bwl1;
    {
        size_t ao = (size_t)(m0+row)*K + khalf*16;
        awh0 = *(const short8*)(Ahi+ao); awh1 = *(const short8*)(Ahi+ao+8);
        awl0 = *(const short8*)(Alo+ao); awl1 = *(const short8*)(Alo+ao+8);
        size_t bo = (size_t)(n0+row)*K + khalf*16;
        bwh0 = *(const short8*)(Bhi+bo); bwh1 = *(const short8*)(Bhi+bo+8);
        bwl0 = *(const short8*)(Blo+bo); bwl1 = *(const short8*)(Blo+bo+8);
    }
    const int NT = K/32;
    for (int kt=0; kt<NT; kt++){
        __syncthreads();
        {
            int base = row*64, sw = row&7;
            int g0 = khalf*2, g1 = khalf*2+1;
            *(short8*)(&As[base + ((g0^sw)<<3)])     = awh0;
            *(short8*)(&As[base + ((g1^sw)<<3)])     = awh1;
            *(short8*)(&As[base + (((g0+4)^sw)<<3)]) = awl0;
            *(short8*)(&As[base + (((g1+4)^sw)<<3)]) = awl1;
            *(short8*)(&Bs[base + ((g0^sw)<<3)])     = bwh0;
            *(short8*)(&Bs[base + ((g1^sw)<<3)])     = bwh1;
            *(short8*)(&Bs[base + (((g0+4)^sw)<<3)]) = bwl0;
            *(short8*)(&Bs[base + (((g1+4)^sw)<<3)]) = bwl1;
        }
        __syncthreads();
        if (kt+1 < NT){
            int k0 = (kt+1)*32;
            size_t ao = (size_t)(m0+row)*K + k0 + khalf*16;
            awh0 = *(const short8*)(Ahi+ao); awh1 = *(const short8*)(Ahi+ao+8);
            awl0 = *(const short8*)(Alo+ao); awl1 = *(const short8*)(Alo+ao+8);
            size_t bo = (size_t)(n0+row)*K + k0 + khalf*16;
            bwh0 = *(const short8*)(Bhi+bo); bwh1 = *(const short8*)(Bhi+bo+8);
            bwl0 = *(const short8*)(Blo+bo); bwl1 = *(const short8*)(Blo+bo+8);
        }
        {
            int kg = lane>>4;
            short8 afh[4], afl[4], bfh[4], bfl[4];
            #pragma unroll
            for (int m=0;m<4;m++){
                int ra = wr*64 + m*16 + (lane&15);
                afh[m] = *(const short8*)(&As[ra*64 + ((kg ^ (ra&7))<<3)]);
                afl[m] = *(const short8*)(&As[ra*64 + (((kg+4) ^ (ra&7))<<3)]);
                int rb = wc*64 + m*16 + (lane&15);
                bfh[m] = *(const short8*)(&Bs[rb*64 + ((kg ^ (rb&7))<<3)]);
                bfl[m] = *(const short8*)(&Bs[rb*64 + (((kg+4) ^ (rb&7))<<3)]);
            }
            #pragma unroll
            for (int m=0;m<4;m++)
                #pragma unroll
                for (int n=0;n<4;n++){
                    acc[m][n] = __builtin_amdgcn_mfma_f32_16x16x32_bf16(afl[m], bfh[n], acc[m][n], 0,0,0);
                    acc[m][n] = __builtin_amdgcn_mfma_f32_16x16x32_bf16(afh[m], bfl[n], acc[m][n], 0,0,0);
                    acc[m][n] = __builtin_amdgcn_mfma_f32_16x16x32_bf16(afh[m], bfh[n], acc[m][n], 0,0,0);
                }
        }
    }
    int colg = n0 + wc*64 + (lane&15);
    int rowg = m0 + wr*64 + ((lane>>4)<<2);
    if (QKV){
        int chunk = n0>>10;
        int colc = colg & 1023;
        const float* bp = chunk==0 ? b0 : (chunk==1 ? b1p : b2p);
        #pragma unroll
        for (int n=0;n<4;n++){
            float bv = bp[colc + n*16];
            #pragma unroll
            for (int m=0;m<4;m++){
                #pragma unroll
                for (int i2=0;i2<4;i2++){
                    int r = rowg + m*16 + i2;
                    float v = acc[m][n][i2] + bv;
                    size_t off = (size_t)r*DD + colc + n*16;
                    if (chunk==0){
                        o0[off] = v*0.125f;
                    } else if (chunk==1){
                        unsigned short hh, ll;
                        split2(v, hh, ll);
                        kh[off]=hh; kl[off]=ll;
                    } else {
                        vh[off] = f2bf(v);   // V stored RN-bf16 single
                    }
                }
            }
        }
    } else {
        #pragma unroll
        for (int n=0;n<4;n++){
            float bv = b0[colg + n*16];
            #pragma unroll
            for (int m=0;m<4;m++){
                #pragma unroll
                for (int i2=0;i2<4;i2++){
                    int r = rowg + m*16 + i2;
                    float v = acc[m][n][i2] + bv + res[(size_t)r*DD + colg + n*16];
                    o0[(size_t)r*DD + colg + n*16] = v;
                }
            }
        }
    }
}

// ---------------- split-bf16x3 MFMA flash attention (unchanged R9) -----------
__global__ __launch_bounds__(512) void attn_mfma(const float* __restrict__ q,
    const unsigned short* __restrict__ khi, const unsigned short* __restrict__ klo,
    const unsigned short* __restrict__ vbf,
    unsigned short* __restrict__ ohi, unsigned short* __restrict__ olo)
{
    __shared__ unsigned short Kh[128*64], Kl[128*64];   // 16KB each
    __shared__ unsigned short Vb[64*128];               // 16KB, transposed [d][s]
    __shared__ unsigned short Ph[8*16*64];              // 16KB, per-wave 16x64 half
    const int tid = threadIdx.x, lane = tid&63, w = tid>>6;   // w: 0..7
    const int t0 = blockIdx.x*128;
    const int b = blockIdx.y>>4, h = blockIdx.y&15;

    short8 qh[2], ql[2];
    #pragma unroll
    for (int kk=0;kk<2;kk++){
        const float* qp = q + ((size_t)(t0 + 16*w + (lane&15))*BB + b)*DD + h*64 + kk*32 + (lane>>4)*8;
        float4 f0 = ((const float4*)qp)[0];
        float4 f1 = ((const float4*)qp)[1];
        unsigned short hh[8], ll[8];
        #pragma unroll
        for (int j=0;j<4;j++){ split2(GETF4(f0,j), hh[j], ll[j]); }
        #pragma unroll
        for (int j=0;j<4;j++){ split2(GETF4(f1,j), hh[4+j], ll[4+j]); }
        qh[kk] = *(short8*)hh; ql[kk] = *(short8*)ll;
    }

    const int kr = tid>>2, kq = tid&3;            // K: row kr (0..127), octets 2kq,2kq+1
    const int vs0 = (tid&63)*2, vd0 = (tid>>6)*8; // V: 2 tokens x 8 dims
    short8 kwh0,kwh1,kwl0,kwl1, vw0,vw1;
    {
        size_t ko = ((size_t)kr*BB + b)*DD + h*64 + kq*16;
        kwh0 = *(const short8*)(khi+ko); kwh1 = *(const short8*)(khi+ko+8);
        kwl0 = *(const short8*)(klo+ko); kwl1 = *(const short8*)(klo+ko+8);
        size_t vo = ((size_t)vs0*BB + b)*DD + h*64 + vd0;
        vw0 = *(const short8*)(vbf+vo);
        vw1 = *(const short8*)(vbf+vo + (size_t)BB*DD);
    }

    float m_st[4] = {-3.0e38f,-3.0e38f,-3.0e38f,-3.0e38f};
    float l_st[4] = {0.f,0.f,0.f,0.f};
    floatx4 zf = {0.f,0.f,0.f,0.f};
    floatx4 oacc[4];
    #pragma unroll
    for (int n=0;n<4;n++) oacc[n]=zf;

    for (int s0=0; s0<TT; s0+=128){
        __syncthreads();
        {
            int base = kr*64, sw = kr&7;
            int g0 = kq*2, g1 = kq*2+1;
            *(short8*)(&Kh[base + ((g0^sw)<<3)]) = kwh0;
            *(short8*)(&Kh[base + ((g1^sw)<<3)]) = kwh1;
            *(short8*)(&Kl[base + ((g0^sw)<<3)]) = kwl0;
            *(short8*)(&Kl[base + ((g1^sw)<<3)]) = kwl1;
        }
        {
            int g = vs0>>3, so = vs0&7;
            #pragma unroll
            for (int j=0;j<8;j++){
                int d = vd0 + j;
                ushort2 pv;
                pv.x = (unsigned short)vw0[j];
                pv.y = (unsigned short)vw1[j];
                *(ushort2*)(&Vb[d*128 + ((g ^ (d&7))<<3) + so]) = pv;
            }
        }
        __syncthreads();
        if (s0+128 < TT){
            size_t ko = ((size_t)(s0+128+kr)*BB + b)*DD + h*64 + kq*16;
            kwh0 = *(const short8*)(khi+ko); kwh1 = *(const short8*)(khi+ko+8);
            kwl0 = *(const short8*)(klo+ko); kwl1 = *(const short8*)(klo+ko+8);
            size_t vo = ((size_t)(s0+128+vs0)*BB + b)*DD + h*64 + vd0;
            vw0 = *(const short8*)(vbf+vo);
            vw1 = *(const short8*)(vbf+vo + (size_t)BB*DD);
        }
        floatx4 sacc[8];
        __builtin_amdgcn_s_setprio(1);
        #pragma unroll
        for (int n=0;n<8;n++){
            floatx4 s = zf;
            #pragma unroll
            for (int kk=0;kk<2;kk++){
                int g = kk*4 + (lane>>4);
                int rb = n*16 + (lane&15);
                short8 kbh = *(const short8*)(&Kh[rb*64 + ((g ^ (rb&7))<<3)]);
                short8 kbl = *(const short8*)(&Kl[rb*64 + ((g ^ (rb&7))<<3)]);
                s = __builtin_amdgcn_mfma_f32_16x16x32_bf16(ql[kk], kbh, s, 0,0,0);
                s = __builtin_amdgcn_mfma_f32_16x16x32_bf16(qh[kk], kbl, s, 0,0,0);
                s = __builtin_amdgcn_mfma_f32_16x16x32_bf16(qh[kk], kbh, s, 0,0,0);
            }
            sacc[n] = s;
        }
        __builtin_amdgcn_s_setprio(0);
        float mx[4];
        #pragma unroll
        for (int r=0;r<4;r++){
            float a0 = fmaxf(fmaxf(sacc[0][r], sacc[1][r]), fmaxf(sacc[2][r], sacc[3][r]));
            float a1 = fmaxf(fmaxf(sacc[4][r], sacc[5][r]), fmaxf(sacc[6][r], sacc[7][r]));
            mx[r] = fmaxf(a0, a1);
        }
        #pragma unroll
        for (int sh=1; sh<16; sh<<=1){
            #pragma unroll
            for (int r=0;r<4;r++) mx[r] = fmaxf(mx[r], __shfl_xor(mx[r], sh));
        }
        float corr[4];
        #pragma unroll
        for (int r=0;r<4;r++){
            float nm = fmaxf(m_st[r], mx[r]);
            corr[r] = __expf(m_st[r] - nm);
            m_st[r] = nm;
        }
        float ts[4] = {0.f,0.f,0.f,0.f};
        #pragma unroll
        for (int n=0;n<8;n++){
            #pragma unroll
            for (int r=0;r<4;r++){
                float p = __expf(sacc[n][r] - m_st[r]);
                ts[r] += p;
                sacc[n][r] = p;
            }
        }
        #pragma unroll
        for (int sh=1; sh<16; sh<<=1){
            #pragma unroll
            for (int r=0;r<4;r++) ts[r] += __shfl_xor(ts[r], sh);
        }
        #pragma unroll
        for (int r=0;r<4;r++) l_st[r] = l_st[r]*corr[r] + ts[r];
        #pragma unroll
        for (int n=0;n<4;n++)
            #pragma unroll
            for (int r=0;r<4;r++) oacc[n][r] *= corr[r];
        #pragma unroll
        for (int half=0; half<2; half++){
            #pragma unroll
            for (int n2=0;n2<4;n2++){
                int n = half*4 + n2;
                #pragma unroll
                for (int r=0;r<4;r++){
                    int q2 = ((lane>>4)<<2) + r;
                    int s2 = n2*16 + (lane&15);
                    int off = w*1024 + q2*64 + (((s2>>3) ^ (q2&7))<<3) + (s2&7);
                    Ph[off] = f2bf(sacc[n][r]);
                }
            }
            __builtin_amdgcn_s_setprio(1);
            #pragma unroll
            for (int kk=0;kk<2;kk++){
                int g = kk*4 + (lane>>4);
                int rq = lane&15;
                short8 pa = *(const short8*)(&Ph[w*1024 + rq*64 + ((g ^ (rq&7))<<3)]);
                #pragma unroll
                for (int n=0;n<4;n++){
                    int rd = n*16 + (lane&15);
                    int gv = half*8 + g;
                    short8 vb = *(const short8*)(&Vb[rd*128 + ((gv ^ (rd&7))<<3)]);
                    oacc[n] = __builtin_amdgcn_mfma_f32_16x16x32_bf16(pa, vb, oacc[n], 0,0,0);
                }
            }
            __builtin_amdgcn_s_setprio(0);
        }
    }
    float il[4];
    #pragma unroll
    for (int r=0;r<4;r++) il[r] = 1.f/l_st[r];
    int qrow = t0 + 16*w + ((lane>>4)<<2);
    #pragma unroll
    for (int n=0;n<4;n++){
        #pragma unroll
        for (int r=0;r<4;r++){
            float v = oacc[n][r]*il[r];
            unsigned short hh, ll;
            split2(v, hh, ll);
            size_t off = ((size_t)(qrow+r)*BB + b)*DD + h*64 + n*16 + (lane&15);
            ohi[off] = hh; olo[off] = ll;
        }
    }
}

// ---------------- transpose+convert bf16 (FFN weights) -----------------------
__global__ __launch_bounds__(256) void transpose_bf16_k(const float* __restrict__ in,
    unsigned short* __restrict__ outp, int R, int C)
{
    __shared__ float t[64][65];
    int e = blockIdx.z;
    const float* ip = in + (size_t)e*R*C;
    unsigned short* op = outp + (size_t)e*R*C;
    int r0 = blockIdx.y*64, c0 = blockIdx.x*64;
    int tid = threadIdx.x;
    #pragma unroll
    for (int i=0;i<4;i++){
        int ch = i*256 + tid;
        int r = ch>>4, c4 = (ch&15)*4;
        float4 v = *(const float4*)(ip + (size_t)(r0+r)*C + c0 + c4);
        t[r][c4+0]=v.x; t[r][c4+1]=v.y; t[r][c4+2]=v.z; t[r][c4+3]=v.w;
    }
    __syncthreads();
    #pragma unroll
    for (int i=0;i<4;i++){
        int ch = i*256 + tid;
        int rr = ch>>4, c4 = (ch&15)*4;
        ushort4 o;
        o.x = f2bf(t[c4+0][rr]); o.y = f2bf(t[c4+1][rr]);
        o.z = f2bf(t[c4+2][rr]); o.w = f2bf(t[c4+3][rr]);
        *(ushort4*)(op + (size_t)(c0+rr)*R + r0 + c4) = o;
    }
}

// ---------------- transpose + split hi/lo (projection weights) ---------------
__global__ __launch_bounds__(256) void transpose_split_k(const float* __restrict__ in,
    unsigned short* __restrict__ oh, unsigned short* __restrict__ ol, int R, int C)
{
    __shared__ float t[64][65];
    int r0 = blockIdx.y*64, c0 = blockIdx.x*64;
    int tid = threadIdx.x;
    #pragma unroll
    for (int i=0;i<4;i++){
        int ch = i*256 + tid;
        int r = ch>>4, c4 = (ch&15)*4;
        float4 v = *(const float4*)(in + (size_t)(r0+r)*C + c0 + c4);
        t[r][c4+0]=v.x; t[r][c4+1]=v.y; t[r][c4+2]=v.z; t[r][c4+3]=v.w;
    }
    __syncthreads();
    #pragma unroll
    for (int i=0;i<4;i++){
        int ch = i*256 + tid;
        int rr = ch>>4, c4 = (ch&15)*4;
        ushort4 hv, lv;
        split2(t[c4+0][rr], hv.x, lv.x);
        split2(t[c4+1][rr], hv.y, lv.y);
        split2(t[c4+2][rr], hv.z, lv.z);
        split2(t[c4+3][rr], hv.w, lv.w);
        size_t off = (size_t)(c0+rr)*R + r0 + c4;
        *(ushort4*)(oh + off) = hv;
        *(ushort4*)(ol + off) = lv;
    }
}

// ---------------- gather dispatch buffer -------------------------------------
__global__ __launch_bounds__(256) void gather_bf16_k(const float* __restrict__ h2,
    const int* __restrict__ s2r, unsigned short* __restrict__ buf)
{
    int s = blockIdx.x; int row = s2r[s]; int c = threadIdx.x;
    float4 v = make_float4(0.f,0.f,0.f,0.f);
    if (row>=0) v = *(const float4*)(h2 + (size_t)row*DD + c*4);
    ushort4 o;
    o.x=f2bf(v.x); o.y=f2bf(v.y); o.z=f2bf(v.z); o.w=f2bf(v.w);
    *(ushort4*)(buf + (size_t)s*DD + c*4) = o;
}

// ---------------- Single-block deterministic scan (unchanged) ----------------
__global__ __launch_bounds__(256) void scan_kernel(
    const float* __restrict__ gates, const int* __restrict__ idx1, const int* __restrict__ idx2,
    const float* __restrict__ g1, const float* __restrict__ g2,
    float* __restrict__ g1n, float* __restrict__ g2n,
    int* __restrict__ f1, int* __restrict__ f2, int* __restrict__ slot2row,
    float* __restrict__ laux)
{
    __shared__ int i1s[SS];
    __shared__ int i2s[SS];
    __shared__ int cnt1[256][EE];
    __shared__ int cnt2[256][EE];
    __shared__ float gsum[256][EE];
    __shared__ int tot1[EE];
    int tid = threadIdx.x;
    for (int i=tid;i<EE*CAP;i+=256) slot2row[i] = -1;
    for (int i=tid;i<SS;i+=256){ i1s[i]=idx1[i]; i2s[i]=idx2[i]; }
    __syncthreads();
    int c1l[EE]={}, c2l[EE]={};
    float gl[EE]={};
    int base = tid*16;
    for (int qq=0;qq<16;qq++){
        int s = base+qq;
        c1l[i1s[s]]++; c2l[i2s[s]]++;
        #pragma unroll
        for (int e2=0;e2<EE;e2++) gl[e2] += gates[(size_t)s*EE+e2];
    }
    #pragma unroll
    for (int e2=0;e2<EE;e2++){ cnt1[tid][e2]=c1l[e2]; cnt2[tid][e2]=c2l[e2]; gsum[tid][e2]=gl[e2]; }
    __syncthreads();
    if (tid < EE){
        int e2 = tid;
        int run=0;
        for (int t=0;t<256;t++){ int tmp=cnt1[t][e2]; cnt1[t][e2]=run; run+=tmp; }
        tot1[e2]=run;
        run=0;
        for (int t=0;t<256;t++){ int tmp=cnt2[t][e2]; cnt2[t][e2]=run; run+=tmp; }
        float gr=0.f;
        for (int t=0;t<256;t++) gr += gsum[t][e2];
        gsum[0][e2]=gr;
    }
    __syncthreads();
    int p1[EE], p2[EE];
    #pragma unroll
    for (int e2=0;e2<EE;e2++){ p1[e2]=cnt1[tid][e2]; p2[e2]=cnt2[tid][e2]+tot1[e2]; }
    for (int qq=0;qq<16;qq++){
        int s = base+qq;
        int e1 = i1s[s], e2v = i2s[s];
        int pos1 = p1[e1]++;
        int pos2 = p2[e2v]++;
        float gv1 = g1[s], gv2 = g2[s];
        float gm1 = (pos1<CAP)? gv1 : 0.f;
        float gm2 = (pos2<CAP)? gv2 : 0.f;
        float den = fmaxf(gm1+gm2, EPSF);
        g1n[s] = gm1/den; g2n[s] = gm2/den;
        int ff1 = e1*CAP + (pos1<CAP?pos1:CAP-1);
        int ff2 = e2v*CAP + (pos2<CAP?pos2:CAP-1);
        f1[s]=ff1; f2[s]=ff2;
        int hrow = (s % TT)*BB + (s / TT);
        if (pos1<CAP) slot2row[ff1]=hrow;
        if (pos2<CAP) slot2row[ff2]=hrow;
    }
    if (tid==0){
        float a=0.f;
        #pragma unroll
        for (int e2=0;e2<EE;e2++) a += (gsum[0][e2]*(1.f/SS)) * ((float)tot1[e2]*(1.f/SS));
        laux[0] = a * (float)EE;
    }
}

// ---------------- Combine (unchanged) ----------------------------------------
__global__ __launch_bounds__(256) void combine_kernel(const float* __restrict__ x2,
    const float* __restrict__ eout, const float* __restrict__ g1n, const float* __restrict__ g2n,
    const int* __restrict__ f1, const int* __restrict__ f2, float* __restrict__ out)
{
    int s = blockIdx.x;
    float a = g1n[s], b = g2n[s];
    int s1 = f1[s], s2 = f2[s];
    int row = (s % TT)*BB + (s / TT);
    int c = threadIdx.x;
    float4 o1 = ((const float4*)(eout + (size_t)s1*DD))[c];
    float4 o2 = ((const float4*)(eout + (size_t)s2*DD))[c];
    float4 xr = ((const float4*)(x2 + (size_t)row*DD))[c];
    float4 r;
    r.x = xr.x + a*o1.x + b*o2.x;
    r.y = xr.y + a*o1.y + b*o2.y;
    r.z = xr.z + a*o1.z + b*o2.z;
    r.w = xr.w + a*o1.w + b*o2.w;
    ((float4*)(out + (size_t)row*DD))[c] = r;
}

extern "C" void kernel_launch(void* const* d_in, const int* in_sizes, int n_in,
                              void* d_out, int out_size, void* d_ws, size_t ws_size,
                              hipStream_t stream)
{
    const float* x    = (const float*)d_in[0];
    const float* Wq   = (const float*)d_in[1];
    const float* bq   = (const float*)d_in[2];
    const float* Wk   = (const float*)d_in[3];
    const float* bk   = (const float*)d_in[4];
    const float* Wv   = (const float*)d_in[5];
    const float* bv   = (const float*)d_in[6];
    const float* Wo   = (const float*)d_in[7];
    const float* bo   = (const float*)d_in[8];
    const float* ln1g = (const float*)d_in[9];
    const float* ln1b = (const float*)d_in[10];
    const float* ln2g = (const float*)d_in[11];
    const float* ln2b = (const float*)d_in[12];
    const float* wgm  = (const float*)d_in[13];
    const float* W1   = (const float*)d_in[14];
    const float* b1   = (const float*)d_in[15];
    const float* W2   = (const float*)d_in[16];
    const float* b2   = (const float*)d_in[17];
    float* out = (float*)d_out;

    char* w = (char*)d_ws;
    unsigned short* h1hi = (unsigned short*)(w);                      // 8MB (later ohi)
    unsigned short* h1lo = (unsigned short*)(w + ((size_t)8<<20));    // 8MB (later olo)
    float*          qb   = (float*)(w + ((size_t)16<<20));     // 16MB (q f32, then h2)
    unsigned short* Khg  = (unsigned short*)(w + ((size_t)32<<20));   // 8MB bf16 [4096][1024]
    unsigned short* Klg  = (unsigned short*)(w + ((size_t)40<<20));   // 8MB
    unsigned short* Vhg  = (unsigned short*)(w + ((size_t)48<<20));   // 8MB (V RN-bf16)
    float*          x2   = (float*)(w + ((size_t)64<<20));     // 16MB
    unsigned short* bufb = (unsigned short*)(w + ((size_t)80<<20));   // 16MB bf16 dispatch
    unsigned short* hb   = (unsigned short*)(w + ((size_t)96<<20));   // 64MB bf16 FFN1 out
    unsigned short* Bqkv_hi = (unsigned short*)(w + ((size_t)96<<20));   // 6MB (dead before FFN1)
    unsigned short* Bqkv_lo = (unsigned short*)(w + ((size_t)102<<20));  // 6MB
    unsigned short* Bo_hi   = (unsigned short*)(w + ((size_t)108<<20));  // 2MB
    unsigned short* Bo_lo   = (unsigned short*)(w + ((size_t)110<<20));  // 2MB
    unsigned short* W1t  = (unsigned short*)(w + ((size_t)160<<20));  // 64MB
    unsigned short* W2t  = (unsigned short*)(w + ((size_t)224<<20));  // 64MB
    float*          ffno = (float*)(w + ((size_t)32<<20));     // 32MB f32 (reuses K/V bufs)
    char*  sm   = w + ((size_t)288<<20);
    float* gates   = (float*)(sm);                sm += (size_t)SS*EE*4;
    int*   idx1    = (int*)(sm);                  sm += SS*4;
    int*   idx2    = (int*)(sm);                  sm += SS*4;
    float* g1      = (float*)(sm);                sm += SS*4;
    float* g2      = (float*)(sm);                sm += SS*4;
    float* g1n     = (float*)(sm);                sm += SS*4;
    float* g2n     = (float*)(sm);                sm += SS*4;
    int*   f1      = (int*)(sm);                  sm += SS*4;
    int*   f2      = (int*)(sm);                  sm += SS*4;
    int*   slot2row= (int*)(sm);                  sm += EE*CAP*4;

    // 0. weight prep
    transpose_bf16_k<<<dim3(FF/64, DD/64, EE), 256, 0, stream>>>(W1, W1t, DD, FF);
    transpose_bf16_k<<<dim3(DD/64, FF/64, EE), 256, 0, stream>>>(W2, W2t, FF, DD);
    transpose_split_k<<<dim3(16,16), 256, 0, stream>>>(Wq, Bqkv_hi,                   Bqkv_lo,                   DD, DD);
    transpose_split_k<<<dim3(16,16), 256, 0, stream>>>(Wk, Bqkv_hi + (size_t)DD*DD,   Bqkv_lo + (size_t)DD*DD,   DD, DD);
    transpose_split_k<<<dim3(16,16), 256, 0, stream>>>(Wv, Bqkv_hi + (size_t)2*DD*DD, Bqkv_lo + (size_t)2*DD*DD, DD, DD);
    transpose_split_k<<<dim3(16,16), 256, 0, stream>>>(Wo, Bo_hi, Bo_lo, DD, DD);
    // 1. LN1 -> pre-split bf16 hi/lo
    ln_split_kernel<<<SS, 256, 0, stream>>>(x, ln1g, ln1b, h1hi, h1lo);
    // 2. fused QKV projection; K split hi/lo, V RN-bf16 (full 3-term compute)
    gemm_mfma_s<true><<<dim3(24, SS/128), 256, 0, stream>>>(
        h1hi, h1lo, Bqkv_hi, Bqkv_lo, bq, bk, bv, nullptr, qb, Khg, Klg, Vhg, SS, DD);
    // 3. attention (128x128 tiles, 8 waves) -> pre-split O hi/lo
    attn_mfma<<<dim3(TT/128, BB*HH), 512, 0, stream>>>(qb, Khg, Klg, Vhg, h1hi, h1lo);
    // 4. O-projection + residual -> x2
    gemm_mfma_s<false><<<dim3(8, SS/128), 256, 0, stream>>>(
        h1hi, h1lo, Bo_hi, Bo_lo, bo, bo, bo, x, x2, nullptr, nullptr, nullptr, SS, DD);
    // 5+6. fused LN2 + routing -> h2 (qb), gates/idx/g1/g2
    ln2_route_kernel<<<SS, 256, 0, stream>>>(x2, ln2g, ln2b, qb,
        wgm, gates, idx1, idx2, g1, g2);
    // 7. scan
    scan_kernel<<<1, 256, 0, stream>>>(gates, idx1, idx2, g1, g2,
        g1n, g2n, f1, f2, slot2row, out + (size_t)SS*DD);
    // 8. gather dispatch buffer
    gather_bf16_k<<<EE*CAP, 256, 0, stream>>>(qb, slot2row, bufb);
    // 9. expert FFN (bf16 MFMA, R11 2-barrier reg-prefetch + XCD swizzle)
    gemm_mfma<true,true><<<dim3(FF/128, (EE*CAP)/128), 256, 0, stream>>>(
        bufb, W1t, b1, nullptr, hb, EE*CAP, FF, DD, (long)FF*DD, FF, CAP);
    gemm_mfma<false,false><<<dim3(DD/128, (EE*CAP)/128), 256, 0, stream>>>(
        hb, W2t, b2, ffno, nullptr, EE*CAP, DD, FF, (long)DD*FF, DD, CAP);
    // 10. combine + residual
    combine_kernel<<<SS, 256, 0, stream>>>(x2, ffno, g1n, g2n, f1, f2, out);
    (void)in_sizes; (void)n_in; (void)out_size; (void)ws_size;
}